// Round 14
// baseline (197.617 us; speedup 1.0000x reference)
//
#include <hip/hip_runtime.h>

#define HDIM 256
#define TDIM 256
#define VOUT 10
#define BC   8     // batch rows per block -> 256 blocks, every CU busy

typedef _Float16 f16x8 __attribute__((ext_vector_type(8)));
typedef float    f32x4 __attribute__((ext_vector_type(4)));

__device__ __forceinline__ float fast_tanh(float a) {
    // tanh(a) = 1 - 2/(exp(2a)+1). |a| bounded (~32) -> no clamp needed.
    float e = __expf(2.0f * a);
    return 1.0f - 2.0f * __builtin_amdgcn_rcpf(e + 1.0f);
}

// pack two f32 -> 2x f16 (RTZ) as a 32-bit word (v_cvt_pkrtz_f16_f32)
__device__ __forceinline__ unsigned pkrtz_u32(float a, float b) {
    auto v = __builtin_amdgcn_cvt_pkrtz(a, b);   // __fp16 ext_vector(2)
    union { decltype(v) h; unsigned u; } cvt;
    cvt.h = v;
    return cvt.u;
}

// v14 = v10 algorithm at 4 waves/block -> 1 wave/SIMD. Per-SIMD pipe totals
// unchanged (32 MFMA, same tanh count), but: no partner wave racing the
// matrix pipe; double per-wave ILP (8 MFMA chains, 16 tanh); tails of
// mt-pair A overlap mt-pair B's matrix drain; 4-wave barrier.
// Wave w owns h-cols [64w, 64w+64) = 4 M-tiles (wfrag 128 VGPR).
__global__ __launch_bounds__(256, 1) void rnn_fwd_v14(
    const float* __restrict__ x,    // [B, T]
    const float* __restrict__ We,   // [H]
    const float* __restrict__ be,   // [H]
    const float* __restrict__ Wh,   // [H, H] (in, out)
    const float* __restrict__ bh,   // [H]
    const float* __restrict__ Wo,   // [H, V]
    const float* __restrict__ bo,   // [V]
    float* __restrict__ out)        // [B, V]
{
    __shared__ __align__(16) char vraw[2][BC * HDIM * 2];   // 2 x 4 KB f16
    __shared__ float x_lds[BC][TDIM + 2];                   // 8.3 KB
    __shared__ float h_fin[BC][HDIM + 1];                   // 8.2 KB

    const int tid = threadIdx.x;
    const int l   = tid & 63;
    const int w   = tid >> 6;       // wave 0..3 -> h-cols [64w, 64w+64)
    const int n   = l & 15;         // MFMA N slot
    const int rn  = n & 7;          // batch row (n>=8 aliases)
    const int hi  = n >> 3;         // rg-pair selector (dedup split)
    const int g   = l >> 4;
    const int r0  = blockIdx.x * BC;

    // ---- stage x (coalesced) ----
    for (int k = tid; k < BC * TDIM; k += 256) {
        int r = k >> 8, t = k & 255;
        x_lds[r][t] = x[(r0 + r) * TDIM + t];
    }

    // ---- W_h -> register fragments (4 M-tiles = 128 VGPR) ----
    // wfrag[mt][kt][e] = Wh[(kt*32+g*8+e)*H + 64w+16mt+n]
    f16x8 wfrag[4][8];
    #pragma unroll
    for (int mt = 0; mt < 4; ++mt) {
        const int col = 64 * w + 16 * mt + n;
        #pragma unroll
        for (int kt = 0; kt < 8; ++kt) {
            #pragma unroll
            for (int e = 0; e < 8; ++e)
                wfrag[mt][kt][e] = (_Float16)Wh[(kt * 32 + g * 8 + e) * HDIM + col];
        }
    }

    // bh as C-init vectors (hcol = 64w+16mt+4g+rg)
    f32x4 bhm[4];
    #pragma unroll
    for (int mt = 0; mt < 4; ++mt)
        #pragma unroll
        for (int rg = 0; rg < 4; ++rg)
            bhm[mt][rg] = bh[64 * w + 16 * mt + 4 * g + rg];

    // ---- own-hcol We/be (direct inp-tanh): hcols 64w+16mt+4g+2hi+{0,1} ----
    float WeO[4][2], beO[4][2];
    #pragma unroll
    for (int mt = 0; mt < 4; ++mt) {
        const int hc = 64 * w + 16 * mt + 4 * g + 2 * hi;
        WeO[mt][0] = We[hc];     beO[mt][0] = be[hc];
        WeO[mt][1] = We[hc + 1]; beO[mt][1] = be[hc + 1];
    }

    // ---- LDS addresses (chunk-major, conflict-free; 2-way max on writes) ----
    const int base_r = g * 128 + rn * 16;              // bfrag: + kt*512
    int addr_w[4];
    #pragma unroll
    for (int mt = 0; mt < 4; ++mt)
        addr_w[mt] = (8 * w + 2 * mt + (g >> 1)) * 128 + rn * 16 + (g & 1) * 8 + hi * 4;

    __syncthreads();

    // ---- v(0) = tanh(x[:,0]*We + be)  (h0 = 0) ----
    {
        const float xv = x_lds[rn][0];
        #pragma unroll
        for (int mt = 0; mt < 4; ++mt) {
            const float s0 = fast_tanh(xv * WeO[mt][0] + beO[mt][0]);
            const float s1 = fast_tanh(xv * WeO[mt][1] + beO[mt][1]);
            *(unsigned*)(&vraw[0][0] + addr_w[mt]) = pkrtz_u32(s0, s1);
        }
    }
    __syncthreads();

    int cur = 0;
    #pragma unroll 1
    for (int t = 0; t < TDIM - 1; ++t) {
        const char* vr = &vraw[cur][0];
        char*       vw = &vraw[cur ^ 1][0];

        // reads: x first (in-order lgkm), then bfrag burst
        const float xv = x_lds[rn][t + 1];
        f16x8 bfrag[8];
        #pragma unroll
        for (int kt = 0; kt < 8; ++kt)
            bfrag[kt] = *(const f16x8*)(vr + base_r + kt * 512);

        // inp-tanh (8 unique values; covers bfrag lgkm wait)
        float ipp[4][2];
        #pragma unroll
        for (int mt = 0; mt < 4; ++mt) {
            ipp[mt][0] = 1.0f + fast_tanh(xv * WeO[mt][0] + beO[mt][0]);
            ipp[mt][1] = 1.0f + fast_tanh(xv * WeO[mt][1] + beO[mt][1]);
        }

        const f32x4 zero = {0.f, 0.f, 0.f, 0.f};
        f32x4 accE[4], accO[4];

        // -- MFMA pair A: mt0+mt1 interleaved (dep distance 4), completes early --
        accE[0] = __builtin_amdgcn_mfma_f32_16x16x32_f16(wfrag[0][0], bfrag[0], bhm[0], 0, 0, 0);
        accE[1] = __builtin_amdgcn_mfma_f32_16x16x32_f16(wfrag[1][0], bfrag[0], bhm[1], 0, 0, 0);
        accO[0] = __builtin_amdgcn_mfma_f32_16x16x32_f16(wfrag[0][1], bfrag[1], zero,   0, 0, 0);
        accO[1] = __builtin_amdgcn_mfma_f32_16x16x32_f16(wfrag[1][1], bfrag[1], zero,   0, 0, 0);
        #pragma unroll
        for (int kp = 1; kp < 4; ++kp) {
            accE[0] = __builtin_amdgcn_mfma_f32_16x16x32_f16(wfrag[0][2 * kp],     bfrag[2 * kp],     accE[0], 0, 0, 0);
            accE[1] = __builtin_amdgcn_mfma_f32_16x16x32_f16(wfrag[1][2 * kp],     bfrag[2 * kp],     accE[1], 0, 0, 0);
            accO[0] = __builtin_amdgcn_mfma_f32_16x16x32_f16(wfrag[0][2 * kp + 1], bfrag[2 * kp + 1], accO[0], 0, 0, 0);
            accO[1] = __builtin_amdgcn_mfma_f32_16x16x32_f16(wfrag[1][2 * kp + 1], bfrag[2 * kp + 1], accO[1], 0, 0, 0);
        }
        // -- MFMA pair B: mt2+mt3 --
        accE[2] = __builtin_amdgcn_mfma_f32_16x16x32_f16(wfrag[2][0], bfrag[0], bhm[2], 0, 0, 0);
        accE[3] = __builtin_amdgcn_mfma_f32_16x16x32_f16(wfrag[3][0], bfrag[0], bhm[3], 0, 0, 0);
        accO[2] = __builtin_amdgcn_mfma_f32_16x16x32_f16(wfrag[2][1], bfrag[1], zero,   0, 0, 0);
        accO[3] = __builtin_amdgcn_mfma_f32_16x16x32_f16(wfrag[3][1], bfrag[1], zero,   0, 0, 0);
        #pragma unroll
        for (int kp = 1; kp < 4; ++kp) {
            accE[2] = __builtin_amdgcn_mfma_f32_16x16x32_f16(wfrag[2][2 * kp],     bfrag[2 * kp],     accE[2], 0, 0, 0);
            accE[3] = __builtin_amdgcn_mfma_f32_16x16x32_f16(wfrag[3][2 * kp],     bfrag[2 * kp],     accE[3], 0, 0, 0);
            accO[2] = __builtin_amdgcn_mfma_f32_16x16x32_f16(wfrag[2][2 * kp + 1], bfrag[2 * kp + 1], accO[2], 0, 0, 0);
            accO[3] = __builtin_amdgcn_mfma_f32_16x16x32_f16(wfrag[3][2 * kp + 1], bfrag[2 * kp + 1], accO[3], 0, 0, 0);
        }

        // -- tails: pair-A tails overlap pair-B matrix drain --
        #pragma unroll
        for (int mt = 0; mt < 4; ++mt) {
            const float a0 = (hi ? accE[mt][2] : accE[mt][0]) + (hi ? accO[mt][2] : accO[mt][0]);
            const float a1 = (hi ? accE[mt][3] : accE[mt][1]) + (hi ? accO[mt][3] : accO[mt][1]);
            const float r0v = __builtin_amdgcn_rcpf(__expf(2.0f * a0) + 1.0f);
            const float r1v = __builtin_amdgcn_rcpf(__expf(2.0f * a1) + 1.0f);
            const float s0 = fmaf(-2.0f, r0v, ipp[mt][0]);
            const float s1 = fmaf(-2.0f, r1v, ipp[mt][1]);
            *(unsigned*)(vw + addr_w[mt]) = pkrtz_u32(s0, s1);
        }
        cur ^= 1;
        __syncthreads();
    }

    // ---- peeled final step: h_fin = tanh(acc) ----
    {
        const char* vr = &vraw[cur][0];
        f16x8 bfrag[8];
        #pragma unroll
        for (int kt = 0; kt < 8; ++kt)
            bfrag[kt] = *(const f16x8*)(vr + base_r + kt * 512);

        const f32x4 zero = {0.f, 0.f, 0.f, 0.f};
        f32x4 accE[4], accO[4];
        #pragma unroll
        for (int mt = 0; mt < 4; ++mt) {
            accE[mt] = __builtin_amdgcn_mfma_f32_16x16x32_f16(wfrag[mt][0], bfrag[0], bhm[mt], 0, 0, 0);
            accO[mt] = __builtin_amdgcn_mfma_f32_16x16x32_f16(wfrag[mt][1], bfrag[1], zero,    0, 0, 0);
        }
        #pragma unroll
        for (int kp = 1; kp < 4; ++kp)
            #pragma unroll
            for (int mt = 0; mt < 4; ++mt) {
                accE[mt] = __builtin_amdgcn_mfma_f32_16x16x32_f16(wfrag[mt][2 * kp],     bfrag[2 * kp],     accE[mt], 0, 0, 0);
                accO[mt] = __builtin_amdgcn_mfma_f32_16x16x32_f16(wfrag[mt][2 * kp + 1], bfrag[2 * kp + 1], accO[mt], 0, 0, 0);
            }
        #pragma unroll
        for (int mt = 0; mt < 4; ++mt) {
            const float a0 = (hi ? accE[mt][2] : accE[mt][0]) + (hi ? accO[mt][2] : accO[mt][0]);
            const float a1 = (hi ? accE[mt][3] : accE[mt][1]) + (hi ? accO[mt][3] : accO[mt][1]);
            const int hc = 64 * w + 16 * mt + 4 * g + 2 * hi;
            h_fin[rn][hc + 0] = fast_tanh(a0);
            h_fin[rn][hc + 1] = fast_tanh(a1);
        }
    }
    __syncthreads();

    // ---- epilogue: out[r][v] = bo[v] + sum_i h[r][i] * Wo[i*V+v] ----
    if (tid < BC * VOUT) {
        const int r = tid / VOUT, vc = tid - r * VOUT;
        float sacc = bo[vc];
        #pragma unroll 8
        for (int i = 0; i < HDIM; ++i)
            sacc = fmaf(h_fin[r][i], Wo[i * VOUT + vc], sacc);
        out[(r0 + r) * VOUT + vc] = sacc;
    }
}

extern "C" void kernel_launch(void* const* d_in, const int* in_sizes, int n_in,
                              void* d_out, int out_size, void* d_ws, size_t ws_size,
                              hipStream_t stream) {
    const float* x  = (const float*)d_in[0];
    const float* We = (const float*)d_in[1];
    const float* be = (const float*)d_in[2];
    const float* Wh = (const float*)d_in[3];
    const float* bh = (const float*)d_in[4];
    const float* Wo = (const float*)d_in[5];
    const float* bo = (const float*)d_in[6];
    float* out = (float*)d_out;

    const int B = in_sizes[0] / TDIM;      // 2048
    const int nblocks = B / BC;            // 256

    rnn_fwd_v14<<<nblocks, 256, 0, stream>>>(x, We, be, Wh, bh, Wo, bo, out);
}

// Round 15
// 169.541 us; speedup vs baseline: 1.1656x; 1.1656x over previous
//
#include <hip/hip_runtime.h>

#define HDIM 256
#define TDIM 256
#define VOUT 10
#define BC   8     // batch rows per block -> 256 blocks, every CU busy

typedef _Float16 f16x8 __attribute__((ext_vector_type(8)));
typedef float    f32x4 __attribute__((ext_vector_type(4)));

__device__ __forceinline__ float fast_tanh(float a) {
    // tanh(a) = 1 - 2/(exp(2a)+1). |a| bounded (~32) -> no clamp needed.
    float e = __expf(2.0f * a);
    return 1.0f - 2.0f * __builtin_amdgcn_rcpf(e + 1.0f);
}

// v15 = v10 (155.4us anchor) + wave-parity anti-phasing: even waves run
// [inp-tanh -> MFMA], odd waves run [MFMA -> inp-tanh] each step. The two
// co-SIMD waves (same block) thus occupy complementary pipes after each
// barrier (VALU/trans vs matrix) instead of phase-locking on the same one.
// No extra work, bitwise-identical arithmetic per element vs v10.
__global__ __launch_bounds__(512, 1) void rnn_fwd_v15(
    const float* __restrict__ x,    // [B, T]
    const float* __restrict__ We,   // [H]
    const float* __restrict__ be,   // [H]
    const float* __restrict__ Wh,   // [H, H] (in, out)
    const float* __restrict__ bh,   // [H]
    const float* __restrict__ Wo,   // [H, V]
    const float* __restrict__ bo,   // [V]
    float* __restrict__ out)        // [B, V]
{
    __shared__ __align__(16) char vraw[2][BC * HDIM * 2];   // 2 x 4 KB f16
    __shared__ float x_lds[BC][TDIM + 2];                   // 8.3 KB
    __shared__ float h_fin[BC][HDIM + 1];                   // 8.2 KB

    const int tid = threadIdx.x;
    const int l   = tid & 63;
    const int w   = tid >> 6;       // wave 0..7 -> h-cols [32w, 32w+32)
    const int n   = l & 15;         // MFMA N slot
    const int rn  = n & 7;          // batch row (n>=8 aliases)
    const int hi  = n >> 3;         // rg-pair selector (dedup split)
    const int g   = l >> 4;
    const int r0  = blockIdx.x * BC;

    // ---- stage x (coalesced) ----
    for (int k = tid; k < BC * TDIM; k += 512) {
        int r = k >> 8, t = k & 255;
        x_lds[r][t] = x[(r0 + r) * TDIM + t];
    }

    // ---- W_h -> register fragments ----
    // wfrag[mt][kt][e] = Wh[(kt*32+g*8+e)*H + 32w+16mt+n]
    f16x8 wfrag[2][8];
    #pragma unroll
    for (int mt = 0; mt < 2; ++mt) {
        const int col = 32 * w + 16 * mt + n;
        #pragma unroll
        for (int kt = 0; kt < 8; ++kt) {
            #pragma unroll
            for (int e = 0; e < 8; ++e)
                wfrag[mt][kt][e] = (_Float16)Wh[(kt * 32 + g * 8 + e) * HDIM + col];
        }
    }

    // bh as C-init vectors (hcol = 32w+16mt+4g+rg)
    f32x4 bh0, bh1;
    #pragma unroll
    for (int rg = 0; rg < 4; ++rg) {
        bh0[rg] = bh[32 * w + 4 * g + rg];
        bh1[rg] = bh[32 * w + 16 + 4 * g + rg];
    }

    // ---- own-hcol We/be (direct inp-tanh): hcols 32w+16mt+4g+2hi+{0,1} ----
    float WeO[2][2], beO[2][2];
    #pragma unroll
    for (int mt = 0; mt < 2; ++mt) {
        const int hc = 32 * w + 16 * mt + 4 * g + 2 * hi;
        WeO[mt][0] = We[hc];     beO[mt][0] = be[hc];
        WeO[mt][1] = We[hc + 1]; beO[mt][1] = be[hc + 1];
    }

    // ---- LDS addresses (chunk-major, conflict-free) ----
    const int base_r = g * 128 + rn * 16;              // bfrag: + kt*512
    int addr_w[2];
    #pragma unroll
    for (int mt = 0; mt < 2; ++mt)
        addr_w[mt] = (4 * w + 2 * mt + (g >> 1)) * 128 + rn * 16 + (g & 1) * 8 + hi * 4;

    __syncthreads();

    // ---- v(0) = tanh(x[:,0]*We + be)  (h0 = 0) ----
    {
        const float xv = x_lds[rn][0];
        #pragma unroll
        for (int mt = 0; mt < 2; ++mt) {
            union { _Float16 h[2]; unsigned u; } pk;
            pk.h[0] = (_Float16)fast_tanh(xv * WeO[mt][0] + beO[mt][0]);
            pk.h[1] = (_Float16)fast_tanh(xv * WeO[mt][1] + beO[mt][1]);
            *(unsigned*)(&vraw[0][0] + addr_w[mt]) = pk.u;
        }
    }
    __syncthreads();

#define IPP_COMPUTE                                                         \
    _Pragma("unroll")                                                       \
    for (int mt = 0; mt < 2; ++mt) {                                        \
        ip[mt][0] = fast_tanh(xv * WeO[mt][0] + beO[mt][0]);                \
        ip[mt][1] = fast_tanh(xv * WeO[mt][1] + beO[mt][1]);                \
    }

#define MFMA_CLUSTER                                                                                      \
    accE0 = __builtin_amdgcn_mfma_f32_16x16x32_f16(wfrag[0][0], bfrag[0], bh0,  0, 0, 0);                 \
    accE1 = __builtin_amdgcn_mfma_f32_16x16x32_f16(wfrag[1][0], bfrag[0], bh1,  0, 0, 0);                 \
    accO0 = __builtin_amdgcn_mfma_f32_16x16x32_f16(wfrag[0][1], bfrag[1], zero, 0, 0, 0);                 \
    accO1 = __builtin_amdgcn_mfma_f32_16x16x32_f16(wfrag[1][1], bfrag[1], zero, 0, 0, 0);                 \
    _Pragma("unroll")                                                                                     \
    for (int kp = 1; kp < 4; ++kp) {                                                                      \
        accE0 = __builtin_amdgcn_mfma_f32_16x16x32_f16(wfrag[0][2 * kp],     bfrag[2 * kp],     accE0, 0, 0, 0); \
        accE1 = __builtin_amdgcn_mfma_f32_16x16x32_f16(wfrag[1][2 * kp],     bfrag[2 * kp],     accE1, 0, 0, 0); \
        accO0 = __builtin_amdgcn_mfma_f32_16x16x32_f16(wfrag[0][2 * kp + 1], bfrag[2 * kp + 1], accO0, 0, 0, 0); \
        accO1 = __builtin_amdgcn_mfma_f32_16x16x32_f16(wfrag[1][2 * kp + 1], bfrag[2 * kp + 1], accO1, 0, 0, 0); \
    }

    const bool mfma_first = (w & 1);

    int cur = 0;
    #pragma unroll 1
    for (int t = 0; t < TDIM - 1; ++t) {
        const char* vr = &vraw[cur][0];
        char*       vw = &vraw[cur ^ 1][0];

        // reads: x first (in-order lgkm), then bfrag burst
        const float xv = x_lds[rn][t + 1];
        f16x8 bfrag[8];
        #pragma unroll
        for (int kt = 0; kt < 8; ++kt)
            bfrag[kt] = *(const f16x8*)(vr + base_r + kt * 512);

        float ip[2][2];
        const f32x4 zero = {0.f, 0.f, 0.f, 0.f};
        f32x4 accE0, accE1, accO0, accO1;

        if (!mfma_first) {
            // even waves: VALU/trans phase first, then matrix
            IPP_COMPUTE;
            MFMA_CLUSTER;
        } else {
            // odd waves: matrix phase first, then VALU/trans
            MFMA_CLUSTER;
            __builtin_amdgcn_sched_barrier(0);  // keep tanh below the MFMA issues
            IPP_COMPUTE;
        }

        // tails (dedup'd: lane handles rg-pair {2hi, 2hi+1}) -- exact v10 math
        {
            const float a0 = (hi ? accE0[2] : accE0[0]) + (hi ? accO0[2] : accO0[0]);
            const float a1 = (hi ? accE0[3] : accE0[1]) + (hi ? accO0[3] : accO0[1]);
            union { _Float16 h[2]; unsigned u; } pk;
            pk.h[0] = (_Float16)(fast_tanh(a0) + ip[0][0]);
            pk.h[1] = (_Float16)(fast_tanh(a1) + ip[0][1]);
            *(unsigned*)(vw + addr_w[0]) = pk.u;
        }
        {
            const float a0 = (hi ? accE1[2] : accE1[0]) + (hi ? accO1[2] : accO1[0]);
            const float a1 = (hi ? accE1[3] : accE1[1]) + (hi ? accO1[3] : accO1[1]);
            union { _Float16 h[2]; unsigned u; } pk;
            pk.h[0] = (_Float16)(fast_tanh(a0) + ip[1][0]);
            pk.h[1] = (_Float16)(fast_tanh(a1) + ip[1][1]);
            *(unsigned*)(vw + addr_w[1]) = pk.u;
        }
        cur ^= 1;
        __syncthreads();
    }

    // ---- peeled final step: h_fin = tanh(acc) ----
    {
        const char* vr = &vraw[cur][0];
        f16x8 bfrag[8];
        #pragma unroll
        for (int kt = 0; kt < 8; ++kt)
            bfrag[kt] = *(const f16x8*)(vr + base_r + kt * 512);

        const f32x4 zero = {0.f, 0.f, 0.f, 0.f};
        f32x4 accE0, accE1, accO0, accO1;
        MFMA_CLUSTER;
        {
            const float a0 = (hi ? accE0[2] : accE0[0]) + (hi ? accO0[2] : accO0[0]);
            const float a1 = (hi ? accE0[3] : accE0[1]) + (hi ? accO0[3] : accO0[1]);
            const int hc = 32 * w + 4 * g + 2 * hi;
            h_fin[rn][hc + 0] = fast_tanh(a0);
            h_fin[rn][hc + 1] = fast_tanh(a1);
        }
        {
            const float a0 = (hi ? accE1[2] : accE1[0]) + (hi ? accO1[2] : accO1[0]);
            const float a1 = (hi ? accE1[3] : accE1[1]) + (hi ? accO1[3] : accO1[1]);
            const int hc = 32 * w + 16 + 4 * g + 2 * hi;
            h_fin[rn][hc + 0] = fast_tanh(a0);
            h_fin[rn][hc + 1] = fast_tanh(a1);
        }
    }
    __syncthreads();

    // ---- epilogue: out[r][v] = bo[v] + sum_i h[r][i] * Wo[i*V+v] ----
    if (tid < BC * VOUT) {
        const int r = tid / VOUT, vc = tid - r * VOUT;
        float sacc = bo[vc];
        #pragma unroll 8
        for (int i = 0; i < HDIM; ++i)
            sacc = fmaf(h_fin[r][i], Wo[i * VOUT + vc], sacc);
        out[(r0 + r) * VOUT + vc] = sacc;
    }
}

extern "C" void kernel_launch(void* const* d_in, const int* in_sizes, int n_in,
                              void* d_out, int out_size, void* d_ws, size_t ws_size,
                              hipStream_t stream) {
    const float* x  = (const float*)d_in[0];
    const float* We = (const float*)d_in[1];
    const float* be = (const float*)d_in[2];
    const float* Wh = (const float*)d_in[3];
    const float* bh = (const float*)d_in[4];
    const float* Wo = (const float*)d_in[5];
    const float* bo = (const float*)d_in[6];
    float* out = (float*)d_out;

    const int B = in_sizes[0] / TDIM;      // 2048
    const int nblocks = B / BC;            // 256

    rnn_fwd_v15<<<nblocks, 512, 0, stream>>>(x, We, be, Wh, bh, Wo, bo, out);
}

// Round 16
// 149.929 us; speedup vs baseline: 1.3181x; 1.1308x over previous
//
#include <hip/hip_runtime.h>

#define HDIM 256
#define TDIM 256
#define VOUT 10
#define BC   8     // batch rows per block -> 256 blocks, every CU busy

typedef _Float16 f16x8 __attribute__((ext_vector_type(8)));
typedef float    f32x4 __attribute__((ext_vector_type(4)));

// tanh from pre-doubled argument: u = 2a -> tanh(a) = 1 - 2/(e^u + 1)
__device__ __forceinline__ float tanh_2a(float u) {
    float e = __expf(u);
    return 1.0f - 2.0f * __builtin_amdgcn_rcpf(e + 1.0f);
}

// pack two f32 -> 2x f16 (RTZ) as a 32-bit word (v_cvt_pkrtz_f16_f32)
__device__ __forceinline__ unsigned pkrtz_u32(float a, float b) {
    auto v = __builtin_amdgcn_cvt_pkrtz(a, b);   // __fp16 ext_vector(2)
    union { decltype(v) h; unsigned u; } cvt;
    cvt.h = v;
    return cvt.u;
}

// v16 = v10 work-shave, bitwise-identical math:
// (1) x2 of exp(2a) folded into Wh/bh/We/be at load (exact scaling) -> no
//     v_mul 2a anywhere; (2) dedup re-sliced by mt: lane owns all 4 rg of
//     mt=hi -> single ds_write_b64 tail (was 2x b32); (3) t-loop unroll 2.
__global__ __launch_bounds__(512, 1) void rnn_fwd_v16(
    const float* __restrict__ x,    // [B, T]
    const float* __restrict__ We,   // [H]
    const float* __restrict__ be,   // [H]
    const float* __restrict__ Wh,   // [H, H] (in, out)
    const float* __restrict__ bh,   // [H]
    const float* __restrict__ Wo,   // [H, V]
    const float* __restrict__ bo,   // [V]
    float* __restrict__ out)        // [B, V]
{
    __shared__ __align__(16) char vraw[2][BC * HDIM * 2];   // 2 x 4 KB f16
    __shared__ float x_lds[BC][TDIM + 2];                   // 8.3 KB
    __shared__ float h_fin[BC][HDIM + 1];                   // 8.2 KB

    const int tid = threadIdx.x;
    const int l   = tid & 63;
    const int w   = tid >> 6;       // wave 0..7 -> h-cols [32w, 32w+32)
    const int n   = l & 15;         // MFMA N slot
    const int rn  = n & 7;          // batch row (n>=8 aliases)
    const int hi  = n >> 3;         // owned m-tile (dedup by mt)
    const int g   = l >> 4;
    const int r0  = blockIdx.x * BC;

    // ---- stage x (coalesced) ----
    for (int k = tid; k < BC * TDIM; k += 512) {
        int r = k >> 8, t = k & 255;
        x_lds[r][t] = x[(r0 + r) * TDIM + t];
    }

    // ---- W_h -> register fragments, scaled by exactly 2 ----
    // wfrag[mt][kt][e] = 2 * Wh[(kt*32+g*8+e)*H + 32w+16mt+n]
    f16x8 wfrag[2][8];
    #pragma unroll
    for (int mt = 0; mt < 2; ++mt) {
        const int col = 32 * w + 16 * mt + n;
        #pragma unroll
        for (int kt = 0; kt < 8; ++kt) {
            #pragma unroll
            for (int e = 0; e < 8; ++e)
                wfrag[mt][kt][e] = (_Float16)(2.0f * Wh[(kt * 32 + g * 8 + e) * HDIM + col]);
        }
    }

    // bh (x2) as C-init vectors (hcol = 32w+16mt+4g+rg)
    f32x4 bh0, bh1;
    #pragma unroll
    for (int rg = 0; rg < 4; ++rg) {
        bh0[rg] = 2.0f * bh[32 * w + 4 * g + rg];
        bh1[rg] = 2.0f * bh[32 * w + 16 + 4 * g + rg];
    }

    // ---- own-hcol We/be (x2): lane owns hcols 32w+16hi+4g+{0..3} ----
    const int hc0 = 32 * w + 16 * hi + 4 * g;
    float WeX[4], beX[4];
    #pragma unroll
    for (int j = 0; j < 4; ++j) {
        WeX[j] = 2.0f * We[hc0 + j];
        beX[j] = 2.0f * be[hc0 + j];
    }

    // ---- LDS addresses (chunk-major, conflict-free) ----
    const int base_r = g * 128 + rn * 16;              // bfrag: + kt*512
    // write: 4 f16 = 8B at chunk 4w+2hi+(g>>1), byte (g&1)*8
    const int addr_w = (4 * w + 2 * hi + (g >> 1)) * 128 + rn * 16 + (g & 1) * 8;

    __syncthreads();

    // ---- v(0) = tanh(x[:,0]*We + be)  (h0 = 0) ----
    {
        const float xv = x_lds[rn][0];
        float s[4];
        #pragma unroll
        for (int j = 0; j < 4; ++j)
            s[j] = tanh_2a(fmaf(xv, WeX[j], beX[j]));
        uint2 pk;
        pk.x = pkrtz_u32(s[0], s[1]);
        pk.y = pkrtz_u32(s[2], s[3]);
        *(uint2*)(&vraw[0][0] + addr_w) = pk;
    }
    __syncthreads();

    int cur = 0;
    #pragma unroll 2
    for (int t = 0; t < TDIM - 1; ++t) {
        const char* vr = &vraw[cur][0];
        char*       vw = &vraw[cur ^ 1][0];

        // reads: x first (in-order lgkm), then bfrag burst
        const float xv = x_lds[rn][t + 1];
        f16x8 bfrag[8];
        #pragma unroll
        for (int kt = 0; kt < 8; ++kt)
            bfrag[kt] = *(const f16x8*)(vr + base_r + kt * 512);

        // ipp = 1 + inp-tanh = 2 - 2*rcp(e+1)  (weights pre-doubled)
        float ipp[4];
        #pragma unroll
        for (int j = 0; j < 4; ++j) {
            const float u = fmaf(xv, WeX[j], beX[j]);
            const float e = __expf(u);
            const float r = __builtin_amdgcn_rcpf(e + 1.0f);
            ipp[j] = fmaf(-2.0f, r, 2.0f);
        }

        // 4 independent 4-deep MFMA chains (v10 order); C-init folds 2*bh / 0
        const f32x4 zero = {0.f, 0.f, 0.f, 0.f};
        f32x4 accE0 = __builtin_amdgcn_mfma_f32_16x16x32_f16(wfrag[0][0], bfrag[0], bh0,  0, 0, 0);
        f32x4 accE1 = __builtin_amdgcn_mfma_f32_16x16x32_f16(wfrag[1][0], bfrag[0], bh1,  0, 0, 0);
        f32x4 accO0 = __builtin_amdgcn_mfma_f32_16x16x32_f16(wfrag[0][1], bfrag[1], zero, 0, 0, 0);
        f32x4 accO1 = __builtin_amdgcn_mfma_f32_16x16x32_f16(wfrag[1][1], bfrag[1], zero, 0, 0, 0);
        #pragma unroll
        for (int kp = 1; kp < 4; ++kp) {
            accE0 = __builtin_amdgcn_mfma_f32_16x16x32_f16(wfrag[0][2 * kp],     bfrag[2 * kp],     accE0, 0, 0, 0);
            accE1 = __builtin_amdgcn_mfma_f32_16x16x32_f16(wfrag[1][2 * kp],     bfrag[2 * kp],     accE1, 0, 0, 0);
            accO0 = __builtin_amdgcn_mfma_f32_16x16x32_f16(wfrag[0][2 * kp + 1], bfrag[2 * kp + 1], accO0, 0, 0, 0);
            accO1 = __builtin_amdgcn_mfma_f32_16x16x32_f16(wfrag[1][2 * kp + 1], bfrag[2 * kp + 1], accO1, 0, 0, 0);
        }

        // tail: lane's own m-tile (mt = hi), all 4 rg; single 8B write
        {
            float sj[4];
            #pragma unroll
            for (int j = 0; j < 4; ++j) {
                const float a = (hi ? accE1[j] : accE0[j]) + (hi ? accO1[j] : accO0[j]);
                const float e = __expf(a);                  // a is pre-doubled via weights
                const float r = __builtin_amdgcn_rcpf(e + 1.0f);
                sj[j] = fmaf(-2.0f, r, ipp[j]);             // tanh + ip
            }
            uint2 pk;
            pk.x = pkrtz_u32(sj[0], sj[1]);
            pk.y = pkrtz_u32(sj[2], sj[3]);
            *(uint2*)(vw + addr_w) = pk;
        }
        cur ^= 1;
        __syncthreads();
    }

    // ---- peeled final step: h_fin = tanh(acc) ----
    {
        const char* vr = &vraw[cur][0];
        f16x8 bfrag[8];
        #pragma unroll
        for (int kt = 0; kt < 8; ++kt)
            bfrag[kt] = *(const f16x8*)(vr + base_r + kt * 512);

        const f32x4 zero = {0.f, 0.f, 0.f, 0.f};
        f32x4 accE0 = __builtin_amdgcn_mfma_f32_16x16x32_f16(wfrag[0][0], bfrag[0], bh0,  0, 0, 0);
        f32x4 accE1 = __builtin_amdgcn_mfma_f32_16x16x32_f16(wfrag[1][0], bfrag[0], bh1,  0, 0, 0);
        f32x4 accO0 = __builtin_amdgcn_mfma_f32_16x16x32_f16(wfrag[0][1], bfrag[1], zero, 0, 0, 0);
        f32x4 accO1 = __builtin_amdgcn_mfma_f32_16x16x32_f16(wfrag[1][1], bfrag[1], zero, 0, 0, 0);
        #pragma unroll
        for (int kp = 1; kp < 4; ++kp) {
            accE0 = __builtin_amdgcn_mfma_f32_16x16x32_f16(wfrag[0][2 * kp],     bfrag[2 * kp],     accE0, 0, 0, 0);
            accE1 = __builtin_amdgcn_mfma_f32_16x16x32_f16(wfrag[1][2 * kp],     bfrag[2 * kp],     accE1, 0, 0, 0);
            accO0 = __builtin_amdgcn_mfma_f32_16x16x32_f16(wfrag[0][2 * kp + 1], bfrag[2 * kp + 1], accO0, 0, 0, 0);
            accO1 = __builtin_amdgcn_mfma_f32_16x16x32_f16(wfrag[1][2 * kp + 1], bfrag[2 * kp + 1], accO1, 0, 0, 0);
        }
        #pragma unroll
        for (int j = 0; j < 4; ++j) {
            const float a = (hi ? accE1[j] : accE0[j]) + (hi ? accO1[j] : accO0[j]);
            h_fin[rn][hc0 + j] = tanh_2a(a);
        }
    }
    __syncthreads();

    // ---- epilogue: out[r][v] = bo[v] + sum_i h[r][i] * Wo[i*V+v] ----
    if (tid < BC * VOUT) {
        const int r = tid / VOUT, vc = tid - r * VOUT;
        float sacc = bo[vc];
        #pragma unroll 8
        for (int i = 0; i < HDIM; ++i)
            sacc = fmaf(h_fin[r][i], Wo[i * VOUT + vc], sacc);
        out[(r0 + r) * VOUT + vc] = sacc;
    }
}

extern "C" void kernel_launch(void* const* d_in, const int* in_sizes, int n_in,
                              void* d_out, int out_size, void* d_ws, size_t ws_size,
                              hipStream_t stream) {
    const float* x  = (const float*)d_in[0];
    const float* We = (const float*)d_in[1];
    const float* be = (const float*)d_in[2];
    const float* Wh = (const float*)d_in[3];
    const float* bh = (const float*)d_in[4];
    const float* Wo = (const float*)d_in[5];
    const float* bo = (const float*)d_in[6];
    float* out = (float*)d_out;

    const int B = in_sizes[0] / TDIM;      // 2048
    const int nblocks = B / BC;            // 256

    rnn_fwd_v16<<<nblocks, 512, 0, stream>>>(x, We, be, Wh, bh, Wo, bo, out);
}